// Round 5
// baseline (179.777 us; speedup 1.0000x reference)
//
#include <hip/hip_runtime.h>

#define D 128
#define LOG2E 1.4426950408889634f
#define LN2   0.6931471805599453f
#define BINS   64
#define BSHIFT 11   // bucket = cand_idx >> 11 -> 2048 rows (1MB) per bucket, 49 used

// ---------- Bucketed path ----------

// K1: per-block bucket histogram (+ bin totals) and segment bounds, fused.
__global__ __launch_bounds__(256) void count_bounds_kernel(
    const int* __restrict__ cand_idx,
    const int* __restrict__ seg_ids,
    int* __restrict__ block_counts,   // [BINS][nblk]
    int* __restrict__ totals,         // [BINS], pre-zeroed via memsetAsync
    int* __restrict__ seg_start,      // [B+1]
    int T, int B, int nblk)
{
    __shared__ int h[BINS];
    const int tid = threadIdx.x;
    if (tid < BINS) h[tid] = 0;
    __syncthreads();

    const int base = blockIdx.x * 1024 + tid * 4;
    #pragma unroll
    for (int j = 0; j < 4; ++j) {
        const int i = base + j;
        if (i < T) atomicAdd(&h[cand_idx[i] >> BSHIFT], 1);
    }
    #pragma unroll
    for (int j = 0; j < 4; ++j) {
        const int i = base + j;
        if (i < T) {
            if (i == 0) seg_start[0] = 0;
            else if (seg_ids[i] != seg_ids[i - 1]) seg_start[seg_ids[i]] = i;
            if (i == T - 1) seg_start[B] = T;
        }
    }
    __syncthreads();
    if (tid < BINS) {
        block_counts[tid * nblk + blockIdx.x] = h[tid];
        atomicAdd(&totals[tid], h[tid]);
    }
}

// K2: one block per bin. bin_start from totals prefix; exclusive scan of the
// bin's per-block counts -> block_base (stable counting sort offsets).
__global__ __launch_bounds__(64) void binscan_kernel(
    const int* __restrict__ block_counts, // [BINS][nblk]
    const int* __restrict__ totals,       // [BINS]
    int* __restrict__ block_base,         // [BINS][nblk]
    int nblk)
{
    const int k    = blockIdx.x;   // bin
    const int lane = threadIdx.x;  // 0..63

    int t = (lane < k) ? totals[lane] : 0;
    #pragma unroll
    for (int off = 32; off >= 1; off >>= 1) t += __shfl_xor(t, off);
    const int bin_start = t;       // uniform across lanes

    // nblk <= 512 -> 8 entries per lane
    const int base = lane * 8;
    int vals[8];
    int s = 0;
    #pragma unroll
    for (int j = 0; j < 8; ++j) {
        const int b = base + j;
        vals[j] = (b < nblk) ? block_counts[k * nblk + b] : 0;
        s += vals[j];
    }
    int inc = s;  // inclusive lane scan
    #pragma unroll
    for (int off = 1; off < 64; off <<= 1) {
        const int up = __shfl_up(inc, off);
        if (lane >= off) inc += up;
    }
    int run = bin_start + (inc - s);
    #pragma unroll
    for (int j = 0; j < 8; ++j) {
        const int b = base + j;
        if (b < nblk) block_base[k * nblk + b] = run;
        run += vals[j];
    }
}

// K3: scatter the stable permutation: perm lists candidate indices grouped by
// cand_idx bucket (ascending block order within bucket).
__global__ __launch_bounds__(256) void scatter_kernel(
    const int* __restrict__ cand_idx,
    const int* __restrict__ block_base,   // [BINS][nblk]
    int* __restrict__ perm,
    int T, int nblk)
{
    __shared__ int h[BINS];
    const int tid = threadIdx.x;
    if (tid < BINS) h[tid] = 0;
    __syncthreads();

    const int base = blockIdx.x * 1024 + tid * 4;
    #pragma unroll
    for (int j = 0; j < 4; ++j) {
        const int i = base + j;
        if (i < T) {
            const int bkt = cand_idx[i] >> BSHIFT;
            const int r   = atomicAdd(&h[bkt], 1);
            perm[block_base[bkt * nblk + blockIdx.x] + r] = i;
        }
    }
}

// K4: logits over the permuted order. Consecutive half-waves process
// consecutive perm entries -> whole GPU works one ~1MB table slice at a time
// (L2-resident gathers). Half-wave (32 lanes x float4) per candidate.
__global__ __launch_bounds__(256) void logits_perm_kernel(
    const float* __restrict__ graph_embed,
    const float* __restrict__ tpl_embedding,
    const int* __restrict__ cand_idx,
    const int* __restrict__ seg_ids,
    const int* __restrict__ perm,
    float* __restrict__ logits,
    int T)
{
    const int sl  = threadIdx.x & 31;
    const int hw  = (blockIdx.x * blockDim.x + threadIdx.x) >> 5;
    const int nhw = (gridDim.x * blockDim.x) >> 5;

    for (int i0 = hw; i0 < T; i0 += 2 * nhw) {
        const int i1   = i0 + nhw;
        const bool has1 = (i1 < T);

        const int t0 = perm[i0];
        const int t1 = has1 ? perm[i1] : t0;

        const int c0 = cand_idx[t0];
        const int s0 = seg_ids[t0];
        const int c1 = cand_idx[t1];
        const int s1 = seg_ids[t1];

        const float4 x0 = ((const float4*)(tpl_embedding + (size_t)c0 * D))[sl];
        const float4 g0 = ((const float4*)(graph_embed   + (size_t)s0 * D))[sl];
        const float4 x1 = ((const float4*)(tpl_embedding + (size_t)c1 * D))[sl];
        const float4 g1 = ((const float4*)(graph_embed   + (size_t)s1 * D))[sl];

        float p0 = fmaf(g0.x, x0.x, fmaf(g0.y, x0.y, fmaf(g0.z, x0.z, g0.w * x0.w)));
        float p1 = fmaf(g1.x, x1.x, fmaf(g1.y, x1.y, fmaf(g1.z, x1.z, g1.w * x1.w)));

        #pragma unroll
        for (int off = 16; off >= 1; off >>= 1) {
            p0 += __shfl_xor(p0, off);
            p1 += __shfl_xor(p1, off);
        }
        if (sl == 0) {
            logits[t0] = p0;
            if (has1) logits[t1] = p1;
        }
    }
}

// ---------- Fallback (no-reorder) logits, used if ws too small ----------
__global__ __launch_bounds__(256) void logits_kernel(
    const float* __restrict__ graph_embed,
    const float* __restrict__ tpl_embedding,
    const int* __restrict__ cand_idx,
    const int* __restrict__ seg_ids,
    float* __restrict__ logits,
    int T)
{
    const int sl  = threadIdx.x & 31;
    const int hw  = (blockIdx.x * blockDim.x + threadIdx.x) >> 5;
    const int nhw = (gridDim.x * blockDim.x) >> 5;

    for (int t0 = hw; t0 < T; t0 += 2 * nhw) {
        const int t1 = t0 + nhw;
        const bool has1 = (t1 < T);
        const int c0 = cand_idx[t0];
        const int s0 = seg_ids[t0];
        const int c1 = has1 ? cand_idx[t1] : c0;
        const int s1 = has1 ? seg_ids[t1] : s0;

        const float4 x0 = ((const float4*)(tpl_embedding + (size_t)c0 * D))[sl];
        const float4 g0 = ((const float4*)(graph_embed   + (size_t)s0 * D))[sl];
        const float4 x1 = ((const float4*)(tpl_embedding + (size_t)c1 * D))[sl];
        const float4 g1 = ((const float4*)(graph_embed   + (size_t)s1 * D))[sl];

        float p0 = fmaf(g0.x, x0.x, fmaf(g0.y, x0.y, fmaf(g0.z, x0.z, g0.w * x0.w)));
        float p1 = fmaf(g1.x, x1.x, fmaf(g1.y, x1.y, fmaf(g1.z, x1.z, g1.w * x1.w)));

        #pragma unroll
        for (int off = 16; off >= 1; off >>= 1) {
            p0 += __shfl_xor(p0, off);
            p1 += __shfl_xor(p1, off);
        }
        if (sl == 0) {
            logits[t0] = p0;
            if (has1) logits[t1] = p1;
        }
    }
}

__global__ void seg_bounds_kernel(const int* __restrict__ seg_ids,
                                  int* __restrict__ seg_start,
                                  int T, int B) {
    int t = blockIdx.x * blockDim.x + threadIdx.x;
    if (t >= T) return;
    if (t == 0) seg_start[0] = 0;
    else if (seg_ids[t] != seg_ids[t - 1]) seg_start[seg_ids[t]] = t;
    if (t == T - 1) seg_start[B] = T;
}

// Phase B: one wave per segment, lane-per-candidate online softmax.
__global__ __launch_bounds__(64) void seg_reduce_kernel(
    const float* __restrict__ logits,
    const int* __restrict__ seg_start,
    const int* __restrict__ target_pos,
    float* __restrict__ out)
{
    const int b    = blockIdx.x;
    const int lane = threadIdx.x;
    const int start = seg_start[b];
    const int end   = seg_start[b + 1];

    float m = -3.0e38f;
    float s = 0.0f;

    for (int t = start + lane; t < end; t += 64) {
        const float x = logits[t] * LOG2E;
        if (x <= m) {
            s += exp2f(x - m);
        } else {
            s = fmaf(s, exp2f(m - x), 1.0f);
            m = x;
        }
    }

    #pragma unroll
    for (int off = 32; off >= 1; off >>= 1) {
        const float m2 = __shfl_xor(m, off);
        const float s2 = __shfl_xor(s, off);
        const float M  = fmaxf(m, m2);
        s = s * exp2f(m - M) + s2 * exp2f(m2 - M);
        m = M;
    }

    if (lane == 0) {
        const float tl = logits[target_pos[b]] * LOG2E;
        out[b] = (tl - m - log2f(s)) * LN2;
    }
}

extern "C" void kernel_launch(void* const* d_in, const int* in_sizes, int n_in,
                              void* d_out, int out_size, void* d_ws, size_t ws_size,
                              hipStream_t stream) {
    const float* graph_embed   = (const float*)d_in[0];
    const float* tpl_embedding = (const float*)d_in[1];
    const int*   cand_idx      = (const int*)d_in[2];
    const int*   seg_ids       = (const int*)d_in[3];
    const int*   target_pos    = (const int*)d_in[4];
    float*       out           = (float*)d_out;

    const int B = in_sizes[0] / D;   // 8192
    const int T = in_sizes[2];       // 524288
    const int nblk = (T + 1023) / 1024;

    // ws layout (256B-aligned chunks)
    size_t off = 0;
    auto alloc = [&](size_t bytes) {
        void* p = (char*)d_ws + off;
        off += (bytes + 255) & ~(size_t)255;
        return p;
    };
    int*   seg_start    = (int*)  alloc((size_t)(B + 1) * 4);
    float* logits       = (float*)alloc((size_t)T * 4);
    int*   perm         = (int*)  alloc((size_t)T * 4);
    int*   block_counts = (int*)  alloc((size_t)BINS * nblk * 4);
    int*   block_base   = (int*)  alloc((size_t)BINS * nblk * 4);
    int*   totals       = (int*)  alloc((size_t)BINS * 4);

    const bool bucketed = (off <= ws_size) && (nblk <= 512);

    if (bucketed) {
        hipMemsetAsync(totals, 0, BINS * 4, stream);
        count_bounds_kernel<<<nblk, 256, 0, stream>>>(cand_idx, seg_ids,
                                                      block_counts, totals,
                                                      seg_start, T, B, nblk);
        binscan_kernel<<<BINS, 64, 0, stream>>>(block_counts, totals,
                                                block_base, nblk);
        scatter_kernel<<<nblk, 256, 0, stream>>>(cand_idx, block_base, perm, T, nblk);
        logits_perm_kernel<<<2048, 256, 0, stream>>>(graph_embed, tpl_embedding,
                                                     cand_idx, seg_ids, perm,
                                                     logits, T);
    } else {
        seg_bounds_kernel<<<(T + 255) / 256, 256, 0, stream>>>(seg_ids, seg_start, T, B);
        logits_kernel<<<2048, 256, 0, stream>>>(graph_embed, tpl_embedding,
                                                cand_idx, seg_ids, logits, T);
    }

    seg_reduce_kernel<<<B, 64, 0, stream>>>(logits, seg_start, target_pos, out);
}

// Round 6
// 165.993 us; speedup vs baseline: 1.0830x; 1.0830x over previous
//
#include <hip/hip_runtime.h>

#define D 128
#define LOG2E 1.4426950408889634f
#define LN2   0.6931471805599453f
#define BINS   64
#define BSHIFT 11   // bucket = cand_idx >> 11 -> 2048 rows (1MB) slice; 49 used

// K1: per-block bucket histogram (+ bin totals) and segment bounds, fused.
__global__ __launch_bounds__(256) void count_bounds_kernel(
    const int* __restrict__ cand_idx,
    const int* __restrict__ seg_ids,
    int* __restrict__ block_counts,   // [BINS][nblk]
    int* __restrict__ totals,         // [BINS], pre-zeroed
    int* __restrict__ seg_start,      // [B+1]
    int T, int B, int nblk)
{
    __shared__ int h[BINS];
    const int tid = threadIdx.x;
    if (tid < BINS) h[tid] = 0;
    __syncthreads();

    const int base = blockIdx.x * 1024 + tid * 4;
    #pragma unroll
    for (int j = 0; j < 4; ++j) {
        const int i = base + j;
        if (i < T) atomicAdd(&h[cand_idx[i] >> BSHIFT], 1);
    }
    #pragma unroll
    for (int j = 0; j < 4; ++j) {
        const int i = base + j;
        if (i < T) {
            if (i == 0) seg_start[0] = 0;
            else if (seg_ids[i] != seg_ids[i - 1]) seg_start[seg_ids[i]] = i;
            if (i == T - 1) seg_start[B] = T;
        }
    }
    __syncthreads();
    if (tid < BINS) {
        block_counts[tid * nblk + blockIdx.x] = h[tid];
        atomicAdd(&totals[tid], h[tid]);
    }
}

// K2: one block per bin; exclusive scan -> stable counting-sort offsets.
__global__ __launch_bounds__(64) void binscan_kernel(
    const int* __restrict__ block_counts, // [BINS][nblk]
    const int* __restrict__ totals,       // [BINS]
    int* __restrict__ block_base,         // [BINS][nblk]
    int nblk)
{
    const int k    = blockIdx.x;
    const int lane = threadIdx.x;

    int t = (lane < k) ? totals[lane] : 0;
    #pragma unroll
    for (int off = 32; off >= 1; off >>= 1) t += __shfl_xor(t, off);
    const int bin_start = t;

    const int base = lane * 8;   // nblk <= 512
    int vals[8];
    int s = 0;
    #pragma unroll
    for (int j = 0; j < 8; ++j) {
        const int b = base + j;
        vals[j] = (b < nblk) ? block_counts[k * nblk + b] : 0;
        s += vals[j];
    }
    int inc = s;
    #pragma unroll
    for (int off = 1; off < 64; off <<= 1) {
        const int up = __shfl_up(inc, off);
        if (lane >= off) inc += up;
    }
    int run = bin_start + (inc - s);
    #pragma unroll
    for (int j = 0; j < 8; ++j) {
        const int b = base + j;
        if (b < nblk) block_base[k * nblk + b] = run;
        run += vals[j];
    }
}

// K3: scatter bucket-ordered PAYLOAD: qarr[i] = {cand, (seg<<19)|t}.
// Writes land in ~(1024/49)-element contiguous runs per block per bucket.
__global__ __launch_bounds__(256) void scatter_kernel(
    const int* __restrict__ cand_idx,
    const int* __restrict__ seg_ids,
    const int* __restrict__ block_base,   // [BINS][nblk]
    int2* __restrict__ qarr,
    int T, int nblk)
{
    __shared__ int h[BINS];
    const int tid = threadIdx.x;
    if (tid < BINS) h[tid] = 0;
    __syncthreads();

    const int base = blockIdx.x * 1024 + tid * 4;
    #pragma unroll
    for (int j = 0; j < 4; ++j) {
        const int i = base + j;
        if (i < T) {
            const int c   = cand_idx[i];
            const int bkt = c >> BSHIFT;
            const int r   = atomicAdd(&h[bkt], 1);
            int2 q;
            q.x = c;
            q.y = (seg_ids[i] << 19) | i;   // seg<8192 (13b), t<2^19
            qarr[block_base[bkt * nblk + blockIdx.x] + r] = q;
        }
    }
}

// K4: consume in bucket order. Sequential qarr stream; tpl gathers hit the
// L2/L3-resident ~1MB bucket slice; graph gathers hit L2/L3 (4MB total).
// Only remaining scatter: 4B logits[t] write. Half-wave per candidate.
__global__ __launch_bounds__(256) void gather_logits_kernel(
    const float* __restrict__ graph_embed,
    const float* __restrict__ tpl_embedding,
    const int2* __restrict__ qarr,
    float* __restrict__ logits,
    int T)
{
    const int sl  = threadIdx.x & 31;
    const int hw  = (blockIdx.x * blockDim.x + threadIdx.x) >> 5;
    const int nhw = (gridDim.x * blockDim.x) >> 5;

    for (int i0 = hw; i0 < T; i0 += 2 * nhw) {
        const int i1   = i0 + nhw;
        const bool has1 = (i1 < T);

        const int2 q0 = qarr[i0];
        const int2 q1 = qarr[has1 ? i1 : i0];

        const int c0 = q0.x, c1 = q1.x;
        const int s0 = (int)((unsigned)q0.y >> 19);
        const int s1 = (int)((unsigned)q1.y >> 19);
        const int t0 = q0.y & 0x7FFFF;
        const int t1 = q1.y & 0x7FFFF;

        const float4 x0 = ((const float4*)(tpl_embedding + (size_t)c0 * D))[sl];
        const float4 g0 = ((const float4*)(graph_embed   + (size_t)s0 * D))[sl];
        const float4 x1 = ((const float4*)(tpl_embedding + (size_t)c1 * D))[sl];
        const float4 g1 = ((const float4*)(graph_embed   + (size_t)s1 * D))[sl];

        float p0 = fmaf(g0.x, x0.x, fmaf(g0.y, x0.y, fmaf(g0.z, x0.z, g0.w * x0.w)));
        float p1 = fmaf(g1.x, x1.x, fmaf(g1.y, x1.y, fmaf(g1.z, x1.z, g1.w * x1.w)));

        #pragma unroll
        for (int off = 16; off >= 1; off >>= 1) {
            p0 += __shfl_xor(p0, off);
            p1 += __shfl_xor(p1, off);
        }
        if (sl == 0) {
            logits[t0] = p0;
            if (has1) logits[t1] = p1;
        }
    }
}

// ---------- Fallback (no-reorder) path ----------
__global__ __launch_bounds__(256) void logits_kernel(
    const float* __restrict__ graph_embed,
    const float* __restrict__ tpl_embedding,
    const int* __restrict__ cand_idx,
    const int* __restrict__ seg_ids,
    float* __restrict__ logits,
    int T)
{
    const int sl  = threadIdx.x & 31;
    const int hw  = (blockIdx.x * blockDim.x + threadIdx.x) >> 5;
    const int nhw = (gridDim.x * blockDim.x) >> 5;

    for (int t0 = hw; t0 < T; t0 += 2 * nhw) {
        const int t1 = t0 + nhw;
        const bool has1 = (t1 < T);
        const int c0 = cand_idx[t0];
        const int s0 = seg_ids[t0];
        const int c1 = has1 ? cand_idx[t1] : c0;
        const int s1 = has1 ? seg_ids[t1] : s0;

        const float4 x0 = ((const float4*)(tpl_embedding + (size_t)c0 * D))[sl];
        const float4 g0 = ((const float4*)(graph_embed   + (size_t)s0 * D))[sl];
        const float4 x1 = ((const float4*)(tpl_embedding + (size_t)c1 * D))[sl];
        const float4 g1 = ((const float4*)(graph_embed   + (size_t)s1 * D))[sl];

        float p0 = fmaf(g0.x, x0.x, fmaf(g0.y, x0.y, fmaf(g0.z, x0.z, g0.w * x0.w)));
        float p1 = fmaf(g1.x, x1.x, fmaf(g1.y, x1.y, fmaf(g1.z, x1.z, g1.w * x1.w)));

        #pragma unroll
        for (int off = 16; off >= 1; off >>= 1) {
            p0 += __shfl_xor(p0, off);
            p1 += __shfl_xor(p1, off);
        }
        if (sl == 0) {
            logits[t0] = p0;
            if (has1) logits[t1] = p1;
        }
    }
}

__global__ void seg_bounds_kernel(const int* __restrict__ seg_ids,
                                  int* __restrict__ seg_start,
                                  int T, int B) {
    int t = blockIdx.x * blockDim.x + threadIdx.x;
    if (t >= T) return;
    if (t == 0) seg_start[0] = 0;
    else if (seg_ids[t] != seg_ids[t - 1]) seg_start[seg_ids[t]] = t;
    if (t == T - 1) seg_start[B] = T;
}

// Phase B: one wave per segment, lane-per-candidate online softmax.
__global__ __launch_bounds__(64) void seg_reduce_kernel(
    const float* __restrict__ logits,
    const int* __restrict__ seg_start,
    const int* __restrict__ target_pos,
    float* __restrict__ out)
{
    const int b    = blockIdx.x;
    const int lane = threadIdx.x;
    const int start = seg_start[b];
    const int end   = seg_start[b + 1];

    float m = -3.0e38f;
    float s = 0.0f;

    for (int t = start + lane; t < end; t += 64) {
        const float x = logits[t] * LOG2E;
        if (x <= m) {
            s += exp2f(x - m);
        } else {
            s = fmaf(s, exp2f(m - x), 1.0f);
            m = x;
        }
    }

    #pragma unroll
    for (int off = 32; off >= 1; off >>= 1) {
        const float m2 = __shfl_xor(m, off);
        const float s2 = __shfl_xor(s, off);
        const float M  = fmaxf(m, m2);
        s = s * exp2f(m - M) + s2 * exp2f(m2 - M);
        m = M;
    }

    if (lane == 0) {
        const float tl = logits[target_pos[b]] * LOG2E;
        out[b] = (tl - m - log2f(s)) * LN2;
    }
}

extern "C" void kernel_launch(void* const* d_in, const int* in_sizes, int n_in,
                              void* d_out, int out_size, void* d_ws, size_t ws_size,
                              hipStream_t stream) {
    const float* graph_embed   = (const float*)d_in[0];
    const float* tpl_embedding = (const float*)d_in[1];
    const int*   cand_idx      = (const int*)d_in[2];
    const int*   seg_ids       = (const int*)d_in[3];
    const int*   target_pos    = (const int*)d_in[4];
    float*       out           = (float*)d_out;

    const int B = in_sizes[0] / D;   // 8192
    const int T = in_sizes[2];       // 524288
    const int nblk = (T + 1023) / 1024;

    size_t off = 0;
    auto alloc = [&](size_t bytes) {
        void* p = (char*)d_ws + off;
        off += (bytes + 255) & ~(size_t)255;
        return p;
    };
    int*   seg_start    = (int*)  alloc((size_t)(B + 1) * 4);
    float* logits       = (float*)alloc((size_t)T * 4);
    int2*  qarr         = (int2*) alloc((size_t)T * 8);
    int*   block_counts = (int*)  alloc((size_t)BINS * nblk * 4);
    int*   block_base   = (int*)  alloc((size_t)BINS * nblk * 4);
    int*   totals       = (int*)  alloc((size_t)BINS * 4);

    const bool bucketed = (off <= ws_size) && (nblk <= 512) && (T < (1 << 19)+1) && (B <= 8192);

    if (bucketed) {
        hipMemsetAsync(totals, 0, BINS * 4, stream);
        count_bounds_kernel<<<nblk, 256, 0, stream>>>(cand_idx, seg_ids,
                                                      block_counts, totals,
                                                      seg_start, T, B, nblk);
        binscan_kernel<<<BINS, 64, 0, stream>>>(block_counts, totals,
                                                block_base, nblk);
        scatter_kernel<<<nblk, 256, 0, stream>>>(cand_idx, seg_ids, block_base,
                                                 qarr, T, nblk);
        gather_logits_kernel<<<2048, 256, 0, stream>>>(graph_embed, tpl_embedding,
                                                       qarr, logits, T);
    } else {
        seg_bounds_kernel<<<(T + 255) / 256, 256, 0, stream>>>(seg_ids, seg_start, T, B);
        logits_kernel<<<2048, 256, 0, stream>>>(graph_embed, tpl_embedding,
                                                cand_idx, seg_ids, logits, T);
    }

    seg_reduce_kernel<<<B, 64, 0, stream>>>(logits, seg_start, target_pos, out);
}

// Round 7
// 133.282 us; speedup vs baseline: 1.3488x; 1.2454x over previous
//
#include <hip/hip_runtime.h>
#include <hip/hip_fp16.h>

#define D 128
#define LOG2E 1.4426950408889634f
#define LN2   0.6931471805599453f

// K0: stream-convert tpl_embedding (fp32) -> fp16 copy in workspace.
// One pass: 51MB read + 26MB write, ~12us. Halves the bytes of every
// subsequent random row gather (the latency/MSHR-capped path).
__global__ __launch_bounds__(256) void tpl_half_kernel(
    const float4* __restrict__ src,
    uint2* __restrict__ dst,
    int n4)
{
    const int stride = gridDim.x * blockDim.x;
    for (int i = blockIdx.x * blockDim.x + threadIdx.x; i < n4; i += stride) {
        const float4 v = src[i];
        const __half2 h01 = __float22half2_rn(make_float2(v.x, v.y));
        const __half2 h23 = __float22half2_rn(make_float2(v.z, v.w));
        uint2 o;
        o.x = *reinterpret_cast<const unsigned*>(&h01);
        o.y = *reinterpret_cast<const unsigned*>(&h23);
        dst[i] = o;
    }
}

// K1: segment bounds from sorted seg_ids -> seg_start[B+1]
__global__ void seg_bounds_kernel(const int* __restrict__ seg_ids,
                                  int* __restrict__ seg_start,
                                  int T, int B) {
    int t = blockIdx.x * blockDim.x + threadIdx.x;
    if (t >= T) return;
    if (t == 0) seg_start[0] = 0;
    else if (seg_ids[t] != seg_ids[t - 1]) seg_start[seg_ids[t]] = t;
    if (t == T - 1) seg_start[B] = T;
}

// K2: logits in t-order (graph reads L1-resident via sorted seg_ids).
// Half-wave (32 lanes) per candidate: tpl fp16 row = 8B/lane (2 lines/row),
// graph fp32 row = 16B/lane. 4-way unroll for lines-in-flight.
__global__ __launch_bounds__(256) void logits_half_kernel(
    const float* __restrict__ graph_embed,
    const __half* __restrict__ tpl_h,
    const int* __restrict__ cand_idx,
    const int* __restrict__ seg_ids,
    float* __restrict__ logits,
    int T)
{
    const int sl  = threadIdx.x & 31;
    const int hw  = (blockIdx.x * blockDim.x + threadIdx.x) >> 5;
    const int nhw = (gridDim.x * blockDim.x) >> 5;

    for (int t0 = hw; t0 < T; t0 += 4 * nhw) {
        int  t[4];
        bool vld[4];
        #pragma unroll
        for (int j = 0; j < 4; ++j) {
            const int tj = t0 + j * nhw;
            vld[j] = (tj < T);
            t[j]   = vld[j] ? tj : t0;
        }

        int c[4], s[4];
        #pragma unroll
        for (int j = 0; j < 4; ++j) { c[j] = cand_idx[t[j]]; s[j] = seg_ids[t[j]]; }

        uint2  x[4];
        float4 g[4];
        #pragma unroll
        for (int j = 0; j < 4; ++j)
            x[j] = ((const uint2*)(tpl_h + (size_t)c[j] * D))[sl];
        #pragma unroll
        for (int j = 0; j < 4; ++j)
            g[j] = ((const float4*)(graph_embed + (size_t)s[j] * D))[sl];

        float p[4];
        #pragma unroll
        for (int j = 0; j < 4; ++j) {
            const float2 f01 = __half22float2(*reinterpret_cast<const __half2*>(&x[j].x));
            const float2 f23 = __half22float2(*reinterpret_cast<const __half2*>(&x[j].y));
            p[j] = fmaf(g[j].x, f01.x,
                   fmaf(g[j].y, f01.y,
                   fmaf(g[j].z, f23.x, g[j].w * f23.y)));
        }

        #pragma unroll
        for (int off = 16; off >= 1; off >>= 1) {
            #pragma unroll
            for (int j = 0; j < 4; ++j)
                p[j] += __shfl_xor(p[j], off);
        }

        if (sl == 0) {
            #pragma unroll
            for (int j = 0; j < 4; ++j)
                if (vld[j]) logits[t[j]] = p[j];
        }
    }
}

// Fallback: fp32 logits (used only if ws can't hold the fp16 table).
__global__ __launch_bounds__(256) void logits_kernel(
    const float* __restrict__ graph_embed,
    const float* __restrict__ tpl_embedding,
    const int* __restrict__ cand_idx,
    const int* __restrict__ seg_ids,
    float* __restrict__ logits,
    int T)
{
    const int sl  = threadIdx.x & 31;
    const int hw  = (blockIdx.x * blockDim.x + threadIdx.x) >> 5;
    const int nhw = (gridDim.x * blockDim.x) >> 5;

    for (int t0 = hw; t0 < T; t0 += 2 * nhw) {
        const int t1 = t0 + nhw;
        const bool has1 = (t1 < T);
        const int c0 = cand_idx[t0];
        const int s0 = seg_ids[t0];
        const int c1 = has1 ? cand_idx[t1] : c0;
        const int s1 = has1 ? seg_ids[t1] : s0;

        const float4 x0 = ((const float4*)(tpl_embedding + (size_t)c0 * D))[sl];
        const float4 g0 = ((const float4*)(graph_embed   + (size_t)s0 * D))[sl];
        const float4 x1 = ((const float4*)(tpl_embedding + (size_t)c1 * D))[sl];
        const float4 g1 = ((const float4*)(graph_embed   + (size_t)s1 * D))[sl];

        float p0 = fmaf(g0.x, x0.x, fmaf(g0.y, x0.y, fmaf(g0.z, x0.z, g0.w * x0.w)));
        float p1 = fmaf(g1.x, x1.x, fmaf(g1.y, x1.y, fmaf(g1.z, x1.z, g1.w * x1.w)));

        #pragma unroll
        for (int off = 16; off >= 1; off >>= 1) {
            p0 += __shfl_xor(p0, off);
            p1 += __shfl_xor(p1, off);
        }
        if (sl == 0) {
            logits[t0] = p0;
            if (has1) logits[t1] = p1;
        }
    }
}

// K3: one wave per segment, lane-per-candidate online softmax.
__global__ __launch_bounds__(64) void seg_reduce_kernel(
    const float* __restrict__ logits,
    const int* __restrict__ seg_start,
    const int* __restrict__ target_pos,
    float* __restrict__ out)
{
    const int b    = blockIdx.x;
    const int lane = threadIdx.x;
    const int start = seg_start[b];
    const int end   = seg_start[b + 1];

    float m = -3.0e38f;
    float s = 0.0f;

    for (int t = start + lane; t < end; t += 64) {
        const float x = logits[t] * LOG2E;
        if (x <= m) {
            s += exp2f(x - m);
        } else {
            s = fmaf(s, exp2f(m - x), 1.0f);
            m = x;
        }
    }

    #pragma unroll
    for (int off = 32; off >= 1; off >>= 1) {
        const float m2 = __shfl_xor(m, off);
        const float s2 = __shfl_xor(s, off);
        const float M  = fmaxf(m, m2);
        s = s * exp2f(m - M) + s2 * exp2f(m2 - M);
        m = M;
    }

    if (lane == 0) {
        const float tl = logits[target_pos[b]] * LOG2E;
        out[b] = (tl - m - log2f(s)) * LN2;
    }
}

extern "C" void kernel_launch(void* const* d_in, const int* in_sizes, int n_in,
                              void* d_out, int out_size, void* d_ws, size_t ws_size,
                              hipStream_t stream) {
    const float* graph_embed   = (const float*)d_in[0];
    const float* tpl_embedding = (const float*)d_in[1];
    const int*   cand_idx      = (const int*)d_in[2];
    const int*   seg_ids       = (const int*)d_in[3];
    const int*   target_pos    = (const int*)d_in[4];
    float*       out           = (float*)d_out;

    const int B  = in_sizes[0] / D;   // 8192
    const int VE = in_sizes[1];       // (V+1)*D elements
    const int T  = in_sizes[2];       // 524288

    size_t off = 0;
    auto alloc = [&](size_t bytes) {
        void* p = (char*)d_ws + off;
        off += (bytes + 255) & ~(size_t)255;
        return p;
    };
    int*    seg_start = (int*)   alloc((size_t)(B + 1) * 4);
    float*  logits    = (float*) alloc((size_t)T * 4);
    __half* tpl_h     = (__half*)alloc((size_t)VE * 2);

    seg_bounds_kernel<<<(T + 255) / 256, 256, 0, stream>>>(seg_ids, seg_start, T, B);

    if (off <= ws_size) {
        tpl_half_kernel<<<2048, 256, 0, stream>>>((const float4*)tpl_embedding,
                                                  (uint2*)tpl_h, VE / 4);
        logits_half_kernel<<<2048, 256, 0, stream>>>(graph_embed, tpl_h,
                                                     cand_idx, seg_ids, logits, T);
    } else {
        logits_kernel<<<2048, 256, 0, stream>>>(graph_embed, tpl_embedding,
                                                cand_idx, seg_ids, logits, T);
    }

    seg_reduce_kernel<<<B, 64, 0, stream>>>(logits, seg_start, target_pos, out);
}

// Round 8
// 124.184 us; speedup vs baseline: 1.4477x; 1.0733x over previous
//
#include <hip/hip_runtime.h>
#include <hip/hip_fp16.h>

#define D 128
#define LOG2E 1.4426950408889634f
#define LN2   0.6931471805599453f

// K0 (fused prep): fp32->fp16 convert tpl + graph tables, and segment bounds.
// All streaming; one launch.
__global__ __launch_bounds__(256) void prep_kernel(
    const float4* __restrict__ tpl_src,   // VE/4 float4s
    const float4* __restrict__ g_src,     // BE/4 float4s
    uint2* __restrict__ tpl_dst,
    uint2* __restrict__ g_dst,
    const int* __restrict__ seg_ids,
    int* __restrict__ seg_start,
    int nt4, int ng4, int T, int B)
{
    const int stride = gridDim.x * blockDim.x;
    const int tid0 = blockIdx.x * blockDim.x + threadIdx.x;

    for (int i = tid0; i < nt4; i += stride) {
        const float4 v = tpl_src[i];
        const __half2 h01 = __float22half2_rn(make_float2(v.x, v.y));
        const __half2 h23 = __float22half2_rn(make_float2(v.z, v.w));
        uint2 o;
        o.x = *reinterpret_cast<const unsigned*>(&h01);
        o.y = *reinterpret_cast<const unsigned*>(&h23);
        tpl_dst[i] = o;
    }
    for (int i = tid0; i < ng4; i += stride) {
        const float4 v = g_src[i];
        const __half2 h01 = __float22half2_rn(make_float2(v.x, v.y));
        const __half2 h23 = __float22half2_rn(make_float2(v.z, v.w));
        uint2 o;
        o.x = *reinterpret_cast<const unsigned*>(&h01);
        o.y = *reinterpret_cast<const unsigned*>(&h23);
        g_dst[i] = o;
    }
    for (int t = tid0; t < T; t += stride) {
        if (t == 0) seg_start[0] = 0;
        else if (seg_ids[t] != seg_ids[t - 1]) seg_start[seg_ids[t]] = t;
        if (t == T - 1) seg_start[B] = T;
    }
}

// K1: logits, quarter-wave (16 lanes x 16B = full 256B fp16 row) per
// candidate. One wave covers 4 candidates per VMEM instruction -> 2x fewer
// gather requests per candidate than half-wave. 2-way unroll.
__global__ __launch_bounds__(256) void logits_q_kernel(
    const __half* __restrict__ graph_h,
    const __half* __restrict__ tpl_h,
    const int* __restrict__ cand_idx,
    const int* __restrict__ seg_ids,
    float* __restrict__ logits,
    int T)
{
    const int sl  = threadIdx.x & 15;                              // lane in quarter-wave
    const int qw  = (blockIdx.x * blockDim.x + threadIdx.x) >> 4;  // quarter-wave id
    const int nqw = (gridDim.x * blockDim.x) >> 4;

    for (int t0 = qw; t0 < T; t0 += 2 * nqw) {
        const int t1   = t0 + nqw;
        const bool has1 = (t1 < T);
        const int ta = t0, tb = has1 ? t1 : t0;

        const int c0 = cand_idx[ta];
        const int s0 = seg_ids[ta];
        const int c1 = cand_idx[tb];
        const int s1 = seg_ids[tb];

        const uint4 x0 = ((const uint4*)(tpl_h   + (size_t)c0 * D))[sl];
        const uint4 g0 = ((const uint4*)(graph_h + (size_t)s0 * D))[sl];
        const uint4 x1 = ((const uint4*)(tpl_h   + (size_t)c1 * D))[sl];
        const uint4 g1 = ((const uint4*)(graph_h + (size_t)s1 * D))[sl];

        float p0 = 0.0f, p1 = 0.0f;
        const __half2* xh0 = (const __half2*)&x0;
        const __half2* gh0 = (const __half2*)&g0;
        const __half2* xh1 = (const __half2*)&x1;
        const __half2* gh1 = (const __half2*)&g1;
        #pragma unroll
        for (int k = 0; k < 4; ++k) {
#if __has_builtin(__builtin_amdgcn_fdot2)
            p0 = __builtin_amdgcn_fdot2(gh0[k], xh0[k], p0, false);
            p1 = __builtin_amdgcn_fdot2(gh1[k], xh1[k], p1, false);
#else
            const float2 xf0 = __half22float2(xh0[k]);
            const float2 gf0 = __half22float2(gh0[k]);
            const float2 xf1 = __half22float2(xh1[k]);
            const float2 gf1 = __half22float2(gh1[k]);
            p0 = fmaf(gf0.x, xf0.x, fmaf(gf0.y, xf0.y, p0));
            p1 = fmaf(gf1.x, xf1.x, fmaf(gf1.y, xf1.y, p1));
#endif
        }

        #pragma unroll
        for (int off = 8; off >= 1; off >>= 1) {
            p0 += __shfl_xor(p0, off);
            p1 += __shfl_xor(p1, off);
        }
        if (sl == 0) {
            logits[ta] = p0;
            if (has1) logits[tb] = p1;
        }
    }
}

// ---------- Fallback (fp32, no conversion) ----------
__global__ void seg_bounds_kernel(const int* __restrict__ seg_ids,
                                  int* __restrict__ seg_start,
                                  int T, int B) {
    int t = blockIdx.x * blockDim.x + threadIdx.x;
    if (t >= T) return;
    if (t == 0) seg_start[0] = 0;
    else if (seg_ids[t] != seg_ids[t - 1]) seg_start[seg_ids[t]] = t;
    if (t == T - 1) seg_start[B] = T;
}

__global__ __launch_bounds__(256) void logits_kernel(
    const float* __restrict__ graph_embed,
    const float* __restrict__ tpl_embedding,
    const int* __restrict__ cand_idx,
    const int* __restrict__ seg_ids,
    float* __restrict__ logits,
    int T)
{
    const int sl  = threadIdx.x & 31;
    const int hw  = (blockIdx.x * blockDim.x + threadIdx.x) >> 5;
    const int nhw = (gridDim.x * blockDim.x) >> 5;

    for (int t0 = hw; t0 < T; t0 += 2 * nhw) {
        const int t1 = t0 + nhw;
        const bool has1 = (t1 < T);
        const int c0 = cand_idx[t0];
        const int s0 = seg_ids[t0];
        const int c1 = has1 ? cand_idx[t1] : c0;
        const int s1 = has1 ? seg_ids[t1] : s0;

        const float4 x0 = ((const float4*)(tpl_embedding + (size_t)c0 * D))[sl];
        const float4 g0 = ((const float4*)(graph_embed   + (size_t)s0 * D))[sl];
        const float4 x1 = ((const float4*)(tpl_embedding + (size_t)c1 * D))[sl];
        const float4 g1 = ((const float4*)(graph_embed   + (size_t)s1 * D))[sl];

        float p0 = fmaf(g0.x, x0.x, fmaf(g0.y, x0.y, fmaf(g0.z, x0.z, g0.w * x0.w)));
        float p1 = fmaf(g1.x, x1.x, fmaf(g1.y, x1.y, fmaf(g1.z, x1.z, g1.w * x1.w)));

        #pragma unroll
        for (int off = 16; off >= 1; off >>= 1) {
            p0 += __shfl_xor(p0, off);
            p1 += __shfl_xor(p1, off);
        }
        if (sl == 0) {
            logits[t0] = p0;
            if (has1) logits[t1] = p1;
        }
    }
}

// K2: one wave per segment, lane-per-candidate online softmax.
__global__ __launch_bounds__(64) void seg_reduce_kernel(
    const float* __restrict__ logits,
    const int* __restrict__ seg_start,
    const int* __restrict__ target_pos,
    float* __restrict__ out)
{
    const int b    = blockIdx.x;
    const int lane = threadIdx.x;
    const int start = seg_start[b];
    const int end   = seg_start[b + 1];

    float m = -3.0e38f;
    float s = 0.0f;

    for (int t = start + lane; t < end; t += 64) {
        const float x = logits[t] * LOG2E;
        if (x <= m) {
            s += exp2f(x - m);
        } else {
            s = fmaf(s, exp2f(m - x), 1.0f);
            m = x;
        }
    }

    #pragma unroll
    for (int off = 32; off >= 1; off >>= 1) {
        const float m2 = __shfl_xor(m, off);
        const float s2 = __shfl_xor(s, off);
        const float M  = fmaxf(m, m2);
        s = s * exp2f(m - M) + s2 * exp2f(m2 - M);
        m = M;
    }

    if (lane == 0) {
        const float tl = logits[target_pos[b]] * LOG2E;
        out[b] = (tl - m - log2f(s)) * LN2;
    }
}

extern "C" void kernel_launch(void* const* d_in, const int* in_sizes, int n_in,
                              void* d_out, int out_size, void* d_ws, size_t ws_size,
                              hipStream_t stream) {
    const float* graph_embed   = (const float*)d_in[0];
    const float* tpl_embedding = (const float*)d_in[1];
    const int*   cand_idx      = (const int*)d_in[2];
    const int*   seg_ids       = (const int*)d_in[3];
    const int*   target_pos    = (const int*)d_in[4];
    float*       out           = (float*)d_out;

    const int BE = in_sizes[0];       // B*D elements
    const int B  = BE / D;            // 8192
    const int VE = in_sizes[1];       // (V+1)*D elements
    const int T  = in_sizes[2];       // 524288

    size_t off = 0;
    auto alloc = [&](size_t bytes) {
        void* p = (char*)d_ws + off;
        off += (bytes + 255) & ~(size_t)255;
        return p;
    };
    int*    seg_start = (int*)   alloc((size_t)(B + 1) * 4);
    float*  logits    = (float*) alloc((size_t)T * 4);
    __half* tpl_h     = (__half*)alloc((size_t)VE * 2);
    __half* graph_h   = (__half*)alloc((size_t)BE * 2);

    if (off <= ws_size) {
        prep_kernel<<<2048, 256, 0, stream>>>((const float4*)tpl_embedding,
                                              (const float4*)graph_embed,
                                              (uint2*)tpl_h, (uint2*)graph_h,
                                              seg_ids, seg_start,
                                              VE / 4, BE / 4, T, B);
        logits_q_kernel<<<2048, 256, 0, stream>>>(graph_h, tpl_h,
                                                  cand_idx, seg_ids, logits, T);
    } else {
        seg_bounds_kernel<<<(T + 255) / 256, 256, 0, stream>>>(seg_ids, seg_start, T, B);
        logits_kernel<<<2048, 256, 0, stream>>>(graph_embed, tpl_embedding,
                                                cand_idx, seg_ids, logits, T);
    }

    seg_reduce_kernel<<<B, 64, 0, stream>>>(logits, seg_start, target_pos, out);
}